// Round 11
// baseline (263.210 us; speedup 1.0000x reference)
//
#include <hip/hip_runtime.h>
#include <stdint.h>

// Problem dims
#define TOKENS 8192      // 4*2048
#define IN_F   3072
#define PAD_F  4096
#define N_OUT  4096
#define K_DIM  4096

using i32x4  = __attribute__((ext_vector_type(4))) int;
using i32x16 = __attribute__((ext_vector_type(16))) int;

// -------- workspace layout (bytes) --------
#define Q_OFF    0
#define WQ_OFF   33554432
#define AINV_OFF 50331648
#define WTOT_OFF 50364416   // u64 fixed-point sum of |w| (x 2^26)

// scale = wtot / 2^26 / 2^24  (16777216 = 4096*4096 weights)
#define WTOT_TO_SCALE (1.0 / (67108864.0 * 16777216.0))

__device__ __forceinline__ void gload_lds16(const void* g, void* l) {
    __builtin_amdgcn_global_load_lds(
        (__attribute__((address_space(1))) void*)(void*)g,
        (__attribute__((address_space(3))) void*)l,
        16, 0, 0);
}

// ---------------- fused K1: [0,8192) LayerNorm+FWHT+quant tokens; [8192,12288) weight-absmean blocks ----------------
__global__ __launch_bounds__(256) void k_fused1(const float* __restrict__ x,
                                                const float* __restrict__ gamma,
                                                const float* __restrict__ beta,
                                                const float* __restrict__ w,
                                                signed char* __restrict__ q,
                                                float* __restrict__ ainv,
                                                unsigned long long* __restrict__ wtot) {
    __shared__ float s[PAD_F];
    __shared__ float rb[8];
    int tid = threadIdx.x;
    int lane = tid & 63;
    int bid = blockIdx.x;

    if (bid >= TOKENS) {
        // ---- weight absmean partial: one 4096-row slice ----
        const float4* w4 = (const float4*)(w + (size_t)(bid - TOKENS) * 4096);
        float sm = 0.f;
#pragma unroll
        for (int i = 0; i < 4; ++i) {
            float4 v = w4[tid + i * 256];
            sm += fabsf(v.x) + fabsf(v.y) + fabsf(v.z) + fabsf(v.w);
        }
#pragma unroll
        for (int o = 32; o > 0; o >>= 1) sm += __shfl_xor(sm, o);
        if ((tid & 63) == 0) rb[tid >> 6] = sm;
        __syncthreads();
        if (tid == 0) {
            float bs = rb[0] + rb[1] + rb[2] + rb[3];
            // u64 fixed-point (x 2^26): integer atomics are exactly order-independent
            atomicAdd(wtot, (unsigned long long)(bs * 67108864.0f));
        }
        return;
    }

    // ---- LayerNorm + pad + FWHT + int8 absmax quant (one token) ----
    int t = bid;
    const float* xr = x + (size_t)t * IN_F;

    float v[16];
    float sum = 0.f;
#pragma unroll
    for (int i = 0; i < 12; ++i) { v[i] = xr[tid + i * 256]; sum += v[i]; }
    v[12] = v[13] = v[14] = v[15] = 0.f;
#pragma unroll
    for (int o = 32; o > 0; o >>= 1) sum += __shfl_xor(sum, o);
    if ((tid & 63) == 0) rb[tid >> 6] = sum;
    __syncthreads();
    float mu = (rb[0] + rb[1] + rb[2] + rb[3]) * (1.0f / 3072.0f);

    float s2 = 0.f;
#pragma unroll
    for (int i = 0; i < 12; ++i) { float d = v[i] - mu; s2 += d * d; }
#pragma unroll
    for (int o = 32; o > 0; o >>= 1) s2 += __shfl_xor(s2, o);
    if ((tid & 63) == 0) rb[4 + (tid >> 6)] = s2;
    __syncthreads();
    float var = (rb[4] + rb[5] + rb[6] + rb[7]) * (1.0f / 3072.0f);
    float rstd = 1.0f / sqrtf(var + 1e-6f);

#pragma unroll
    for (int i = 0; i < 12; ++i)
        v[i] = (v[i] - mu) * rstd * gamma[tid + i * 256] + beta[tid + i * 256];

    // FWHT group 1: bits 8-11 (register index i)
#pragma unroll
    for (int b = 1; b < 16; b <<= 1) {
#pragma unroll
        for (int i = 0; i < 16; ++i) {
            if (!(i & b)) {
                float a0 = v[i], b0 = v[i | b];
                v[i] = a0 + b0;
                v[i | b] = a0 - b0;
            }
        }
    }
    // group 2: bits 0-5 (lane) via shfl_xor
#pragma unroll
    for (int m = 1; m <= 32; m <<= 1) {
#pragma unroll
        for (int i = 0; i < 16; ++i) {
            float p = __shfl_xor(v[i], m);
            v[i] = (lane & m) ? (p - v[i]) : (v[i] + p);
        }
    }
    // group 3: bits 6-7 (wave id) via LDS
#pragma unroll
    for (int m = 64; m <= 128; m <<= 1) {
        __syncthreads();
#pragma unroll
        for (int i = 0; i < 16; ++i) s[tid + i * 256] = v[i];
        __syncthreads();
#pragma unroll
        for (int i = 0; i < 16; ++i) {
            float p = s[(tid ^ m) + i * 256];
            v[i] = (tid & m) ? (p - v[i]) : (v[i] + p);
        }
    }

    // absmax of fwht/64
    float mx = 0.f;
#pragma unroll
    for (int i = 0; i < 16; ++i) mx = fmaxf(mx, fabsf(v[i]));
#pragma unroll
    for (int o = 32; o > 0; o >>= 1) mx = fmaxf(mx, __shfl_xor(mx, o));
    __syncthreads();
    if ((tid & 63) == 0) rb[tid >> 6] = mx;
    __syncthreads();
    float amraw = fmaxf(fmaxf(rb[0], rb[1]), fmaxf(rb[2], rb[3]));
    float amax = fmaxf(amraw * (1.0f / 64.0f), 1e-5f);
    float scale = 127.0f / amax;
    if (tid == 0) ainv[t] = amax * (1.0f / 127.0f);

    signed char* qr = q + (size_t)t * PAD_F;
#pragma unroll
    for (int i = 0; i < 16; ++i) {
        int qi = (int)rintf(v[i] * (1.0f / 64.0f) * scale);
        qi = max(-128, min(127, qi));
        qr[tid + i * 256] = (signed char)qi;
    }
}

// ---------------- ternary weight quant (scale from u64 total) ----------------
__global__ __launch_bounds__(256) void k_wquant(const float* __restrict__ w,
                                                const unsigned long long* __restrict__ wtot,
                                                unsigned int* __restrict__ wq) {
    int idx = blockIdx.x * 256 + threadIdx.x;   // float4 group index
    float ws = (float)fmax((double)(*wtot) * WTOT_TO_SCALE, 1e-5);
    float4 v = ((const float4*)w)[idx];
    int a = (int)rintf(v.x / ws); a = max(-1, min(1, a));
    int b = (int)rintf(v.y / ws); b = max(-1, min(1, b));
    int c = (int)rintf(v.z / ws); c = max(-1, min(1, c));
    int d = (int)rintf(v.w / ws); d = max(-1, min(1, d));
    unsigned int p = (unsigned)(a & 255) | ((unsigned)(b & 255) << 8) |
                     ((unsigned)(c & 255) << 16) | ((unsigned)(d & 255) << 24);
    wq[idx] = p;
}

// ---------------- int8 MFMA GEMM, 256x256 tile, BK=64, paired-row LDS, 32x32x32 ----------------
// out[m][n] = (sum_k q[m][k]*t[n][k]) * wsc * ainv[m]
// Round-6 structure verbatim (4-buffer ring, VMW(8), 1 barrier/tile, reg-dbuf
// fragments, paired-row LDS: row r (128B) holds matrix rows {2r,2r+1}, chunk
// (par,h) at slot (par*4+h)^(r&7), pre-swizzled global staging, rule #21).
// CHANGED: mfma_i32_32x32x32_i8 (4404 vs 3944 TOPS; 16 vs 32 MFMA/wave/tile).
// 32-row fragment read: lane(r32=lane&31, ks=lane>>5), h = kk*2+ks,
// slot = (par*4+h)^((r32>>1)&7) -> 8 lanes/4-bank-group, 2/bank distinct = free.
#define BK 64
#define NT (K_DIM / BK)   // 64

#define VMW(n) asm volatile("s_waitcnt vmcnt(" #n ")" ::: "memory")
#define SB0()  __builtin_amdgcn_sched_barrier(0)

__global__ __launch_bounds__(512, 2) void k_gemm(const signed char* __restrict__ Aq,
                                                 const signed char* __restrict__ Wq,
                                                 const float* __restrict__ ainv,
                                                 const unsigned long long* __restrict__ wtot,
                                                 float* __restrict__ out) {
    __shared__ signed char sA[4][128 * 128];   // 4 x 16 KB (256 rows -> 128 LDS-rows)
    __shared__ signed char sB[4][128 * 128];

    int tid = threadIdx.x;
    int lane = tid & 63, wid = tid >> 6;

    // XCD partition: XCD x owns bm in {4x..4x+3} (A L2-resident), sweeps bn.
    int bid = blockIdx.x;
    int xcd = bid & 7, li = bid >> 3;
    int bmb = xcd * 4 + (li & 3);
    int bnb = li >> 2;
    size_t bm0 = (size_t)bmb * 256, bn0 = (size_t)bnb * 256;

    int wm = wid >> 2, wn = wid & 3;          // 2M x 4N waves; wave tile 128x64

    // ---- staging decode (round-6 verified): lane l -> byte l*16 of 1KB seg ----
    int rr = lane >> 3, pp = lane & 7;
    int Lg = pp ^ rr;
    int spar = Lg >> 2, sh = Lg & 3;
    const signed char* gA = Aq + (bm0 + (size_t)(wid * 32 + 2 * rr + spar)) * K_DIM + sh * 16;
    const signed char* gB = Wq + (bn0 + (size_t)(wid * 32 + 2 * rr + spar)) * K_DIM + sh * 16;

    // ---- 32x32x32 fragment read constants ----
    int r32 = lane & 31, ks = lane >> 5;       // frag row (A) / col (B); K 16B-half
    int q7 = (r32 >> 1) & 7;
    int pq = ((r32 & 1) << 2) | ks;            // par*4 + ks
    int pos0 = pq ^ q7;                        // kk=0 slot
    int pos1 = (pq | 2) ^ q7;                  // kk=1 slot (h = kk*2+ks, no carry)
    int abase = (wm * 64 + (r32 >> 1)) * 8;    // + mf*128 + pos{kk}
    int bbase = (wn * 32 + (r32 >> 1)) * 8;    // + nf*128 + pos{kk}

    i32x16 acc[4][2];
#pragma unroll
    for (int m = 0; m < 4; ++m)
#pragma unroll
        for (int n = 0; n < 2; ++n) acc[m][n] = (i32x16)(0);

    i32x4 afA[2][4], bfA[2][2], afB[2][4], bfB[2][2];

    auto STAGE = [&](int b, int t) {
        size_t k0 = (size_t)t * BK;
        gload_lds16(gA + k0, &sA[b][(wid * 16) * 128]);
        gload_lds16(gA + k0 + (size_t)16 * K_DIM, &sA[b][(wid * 16 + 8) * 128]);
        gload_lds16(gB + k0, &sB[b][(wid * 16) * 128]);
        gload_lds16(gB + k0 + (size_t)16 * K_DIM, &sB[b][(wid * 16 + 8) * 128]);
    };

#define LOADF(Bb, AF, BF) do {                                          \
    const i32x4* va = (const i32x4*)&sA[Bb][0];                         \
    const i32x4* vb = (const i32x4*)&sB[Bb][0];                         \
    _Pragma("unroll")                                                   \
    for (int mf = 0; mf < 4; ++mf) {                                    \
        AF[0][mf] = va[abase + mf * 128 + pos0];                        \
        AF[1][mf] = va[abase + mf * 128 + pos1];                        \
    }                                                                   \
    _Pragma("unroll")                                                   \
    for (int nf = 0; nf < 2; ++nf) {                                    \
        BF[0][nf] = vb[bbase + nf * 128 + pos0];                        \
        BF[1][nf] = vb[bbase + nf * 128 + pos1];                        \
    }                                                                   \
} while (0)

#define COMPUTE(AF, BF) do {                                            \
    __builtin_amdgcn_s_setprio(1);                                      \
    _Pragma("unroll")                                                   \
    for (int kk = 0; kk < 2; ++kk)                                      \
        _Pragma("unroll")                                               \
        for (int mf = 0; mf < 4; ++mf)                                  \
            _Pragma("unroll")                                           \
            for (int nf = 0; nf < 2; ++nf)                              \
                acc[mf][nf] = __builtin_amdgcn_mfma_i32_32x32x32_i8(    \
                    AF[kk][mf], BF[kk][nf], acc[mf][nf], 0, 0, 0);      \
    __builtin_amdgcn_s_setprio(0);                                      \
} while (0)

#define BODY(T, AFC, BFC, AFN, BFN) do {                                \
    STAGE((T + 3) & 3, T + 3);                                          \
    VMW(8);                                                             \
    SB0();                                                              \
    __builtin_amdgcn_s_barrier();                                       \
    SB0();                                                              \
    LOADF((T + 1) & 3, AFN, BFN);                                       \
    COMPUTE(AFC, BFC);                                                  \
    asm volatile("s_waitcnt lgkmcnt(0)" ::: "memory");                  \
    SB0();                                                              \
} while (0)

    // prologue: 3 tiles in flight, tile 0 certified, frags(0) -> A set
    STAGE(0, 0);
    STAGE(1, 1);
    STAGE(2, 2);
    VMW(8);
    SB0();
    __builtin_amdgcn_s_barrier();
    SB0();
    LOADF(0, afA, bfA);
    asm volatile("s_waitcnt lgkmcnt(0)" ::: "memory");
    SB0();

#pragma unroll 1
    for (int t = 0; t < NT - 4; t += 2) {
        BODY(t, afA, bfA, afB, bfB);
        BODY(t + 1, afB, bfB, afA, bfA);
    }
    // t = 60: stages tile 63 (VMW(8) certifies 61), computes 60
    BODY(NT - 4, afA, bfA, afB, bfB);
    // t = 61: in-flight 62,63 -> VMW(4) certifies 62
    VMW(4);
    SB0();
    __builtin_amdgcn_s_barrier();
    SB0();
    LOADF(2, afA, bfA);
    COMPUTE(afB, bfB);
    asm volatile("s_waitcnt lgkmcnt(0)" ::: "memory");
    SB0();
    // t = 62: VMW(0) certifies 63
    VMW(0);
    SB0();
    __builtin_amdgcn_s_barrier();
    SB0();
    LOADF(3, afB, bfB);
    COMPUTE(afA, bfA);
    asm volatile("s_waitcnt lgkmcnt(0)" ::: "memory");
    SB0();
    // t = 63
    COMPUTE(afB, bfB);

    // epilogue: 32x32 C/D layout: col = lane&31, row = (reg&3)+8*(reg>>2)+4*(lane>>5)
    float wsc = (float)fmax((double)(*wtot) * WTOT_TO_SCALE, 1e-5);
    int c31 = lane & 31, hi2 = lane >> 5;
#pragma unroll
    for (int mf = 0; mf < 4; ++mf) {
        size_t rowb = bm0 + wm * 128 + mf * 32 + 4 * hi2;
#pragma unroll
        for (int reg = 0; reg < 16; ++reg) {
            size_t row = rowb + (reg & 3) + 8 * (reg >> 2);
            float sa = wsc * ainv[row];
#pragma unroll
            for (int nf = 0; nf < 2; ++nf) {
                size_t col = bn0 + wn * 64 + nf * 32 + c31;
                out[row * N_OUT + col] = (float)acc[mf][nf][reg] * sa;
            }
        }
    }
#undef LOADF
#undef COMPUTE
#undef BODY
}

extern "C" void kernel_launch(void* const* d_in, const int* in_sizes, int n_in,
                              void* d_out, int out_size, void* d_ws, size_t ws_size,
                              hipStream_t stream) {
    const float* x     = (const float*)d_in[0];
    const float* gamma = (const float*)d_in[1];
    const float* beta  = (const float*)d_in[2];
    const float* w     = (const float*)d_in[3];
    float* out = (float*)d_out;
    char* ws = (char*)d_ws;

    signed char* q   = (signed char*)(ws + Q_OFF);
    signed char* wq  = (signed char*)(ws + WQ_OFF);
    float* ainv      = (float*)(ws + AINV_OFF);
    unsigned long long* wtot = (unsigned long long*)(ws + WTOT_OFF);

    hipMemsetAsync((void*)wtot, 0, 8, stream);
    k_fused1<<<dim3(TOKENS + 4096), dim3(256), 0, stream>>>(x, gamma, beta, w, q, ainv, wtot);
    k_wquant<<<dim3(16384), dim3(256), 0, stream>>>(w, wtot, (unsigned int*)wq);
    k_gemm<<<dim3(512), dim3(512), 0, stream>>>(q, wq, ainv, wtot, out);
}

// Round 12
// 212.606 us; speedup vs baseline: 1.2380x; 1.2380x over previous
//
#include <hip/hip_runtime.h>
#include <stdint.h>

// Problem dims
#define TOKENS 8192      // 4*2048
#define IN_F   3072
#define PAD_F  4096
#define N_OUT  4096
#define K_DIM  4096

using i32x4 = __attribute__((ext_vector_type(4))) int;

// -------- workspace layout (bytes) --------
#define Q_OFF    0
#define WQ_OFF   33554432
#define AINV_OFF 50331648
#define PART_OFF 50364416
#define WSC_OFF  50380800

__device__ __forceinline__ void gload_lds16(const void* g, void* l) {
    __builtin_amdgcn_global_load_lds(
        (__attribute__((address_space(1))) void*)(void*)g,
        (__attribute__((address_space(3))) void*)l,
        16, 0, 0);
}

// ---------------- weight absmean: partial sums ----------------
__global__ __launch_bounds__(256) void k_wabs(const float* __restrict__ w,
                                              float* __restrict__ partial) {
    int tid = threadIdx.x;
    const float4* w4 = (const float4*)(w + (size_t)blockIdx.x * 4096);
    float s = 0.f;
#pragma unroll
    for (int i = 0; i < 4; ++i) {
        float4 v = w4[tid + i * 256];
        s += fabsf(v.x) + fabsf(v.y) + fabsf(v.z) + fabsf(v.w);
    }
#pragma unroll
    for (int o = 32; o > 0; o >>= 1) s += __shfl_xor(s, o);
    __shared__ float rb[4];
    if ((tid & 63) == 0) rb[tid >> 6] = s;
    __syncthreads();
    if (tid == 0) partial[blockIdx.x] = rb[0] + rb[1] + rb[2] + rb[3];
}

// ---------------- finalize weight scale ----------------
__global__ __launch_bounds__(256) void k_wscale(const float* __restrict__ partial,
                                                float* __restrict__ wsp) {
    int tid = threadIdx.x;
    float s = 0.f;
#pragma unroll
    for (int i = 0; i < 16; ++i) s += partial[tid + i * 256];
#pragma unroll
    for (int o = 32; o > 0; o >>= 1) s += __shfl_xor(s, o);
    __shared__ float rb[4];
    if ((tid & 63) == 0) rb[tid >> 6] = s;
    __syncthreads();
    if (tid == 0)
        wsp[0] = fmaxf((rb[0] + rb[1] + rb[2] + rb[3]) * (1.0f / 16777216.0f), 1e-5f);
}

// ---------------- ternary weight quant ----------------
__global__ __launch_bounds__(256) void k_wquant(const float* __restrict__ w,
                                                const float* __restrict__ wsp,
                                                unsigned int* __restrict__ wq) {
    int idx = blockIdx.x * 256 + threadIdx.x;   // float4 group index
    float ws = wsp[0];
    float4 v = ((const float4*)w)[idx];
    int a = (int)rintf(v.x / ws); a = max(-1, min(1, a));
    int b = (int)rintf(v.y / ws); b = max(-1, min(1, b));
    int c = (int)rintf(v.z / ws); c = max(-1, min(1, c));
    int d = (int)rintf(v.w / ws); d = max(-1, min(1, d));
    unsigned int p = (unsigned)(a & 255) | ((unsigned)(b & 255) << 8) |
                     ((unsigned)(c & 255) << 16) | ((unsigned)(d & 255) << 24);
    wq[idx] = p;
}

// ---------------- fused LayerNorm + pad + FWHT + int8 absmax quant ----------------
// ROUND 12: fully vectorized I/O. Slot s = c + 4*tid + 1024*i (c in [0,4), i in [0,4)).
// Loads: 3x float4 (x, gamma, beta); stores: 4x packed u32 (vs 16 byte-stores).
// FWHT bit-split: bits 0-1 (c) + 10-11 (i) in-register, bits 2-7 (lane) shfl_xor,
// bits 8-9 (wave) via LDS. Stage order irrelevant for Hadamard (round-2 verified).
__global__ __launch_bounds__(256) void k_lnfwht(const float* __restrict__ x,
                                                const float* __restrict__ gamma,
                                                const float* __restrict__ beta,
                                                signed char* __restrict__ q,
                                                float* __restrict__ ainv) {
    __shared__ float s[PAD_F];
    __shared__ float rb[8];
    int tid = threadIdx.x;
    int lane = tid & 63;
    int t = blockIdx.x;
    const float4* xr4 = (const float4*)(x + (size_t)t * IN_F);
    const float4* g4  = (const float4*)gamma;
    const float4* b4  = (const float4*)beta;

    float v[16];
    float sum = 0.f;
#pragma unroll
    for (int i = 0; i < 3; ++i) {
        float4 xv = xr4[tid + i * 256];
        v[4 * i + 0] = xv.x; v[4 * i + 1] = xv.y;
        v[4 * i + 2] = xv.z; v[4 * i + 3] = xv.w;
        sum += xv.x + xv.y + xv.z + xv.w;
    }
    v[12] = v[13] = v[14] = v[15] = 0.f;
#pragma unroll
    for (int o = 32; o > 0; o >>= 1) sum += __shfl_xor(sum, o);
    if (lane == 0) rb[tid >> 6] = sum;
    __syncthreads();
    float mu = (rb[0] + rb[1] + rb[2] + rb[3]) * (1.0f / 3072.0f);

    float s2 = 0.f;
#pragma unroll
    for (int i = 0; i < 12; ++i) { float d = v[i] - mu; s2 += d * d; }
#pragma unroll
    for (int o = 32; o > 0; o >>= 1) s2 += __shfl_xor(s2, o);
    if (lane == 0) rb[4 + (tid >> 6)] = s2;
    __syncthreads();
    float var = (rb[4] + rb[5] + rb[6] + rb[7]) * (1.0f / 3072.0f);
    float rstd = 1.0f / sqrtf(var + 1e-6f);

#pragma unroll
    for (int i = 0; i < 3; ++i) {
        float4 gv = g4[tid + i * 256];
        float4 bv = b4[tid + i * 256];
        v[4 * i + 0] = (v[4 * i + 0] - mu) * rstd * gv.x + bv.x;
        v[4 * i + 1] = (v[4 * i + 1] - mu) * rstd * gv.y + bv.y;
        v[4 * i + 2] = (v[4 * i + 2] - mu) * rstd * gv.z + bv.z;
        v[4 * i + 3] = (v[4 * i + 3] - mu) * rstd * gv.w + bv.w;
    }

    // FWHT bits 0-1 (c, in-register 4-point transforms)
#pragma unroll
    for (int i = 0; i < 4; ++i) {
        float a0 = v[4 * i], a1 = v[4 * i + 1], a2 = v[4 * i + 2], a3 = v[4 * i + 3];
        float t0 = a0 + a1, t1 = a0 - a1, t2 = a2 + a3, t3 = a2 - a3;
        v[4 * i] = t0 + t2; v[4 * i + 1] = t1 + t3;
        v[4 * i + 2] = t0 - t2; v[4 * i + 3] = t1 - t3;
    }
    // FWHT bits 10-11 (i, in-register 4-point transforms)
#pragma unroll
    for (int c = 0; c < 4; ++c) {
        float a0 = v[c], a1 = v[4 + c], a2 = v[8 + c], a3 = v[12 + c];
        float t0 = a0 + a1, t1 = a0 - a1, t2 = a2 + a3, t3 = a2 - a3;
        v[c] = t0 + t2; v[4 + c] = t1 + t3;
        v[8 + c] = t0 - t2; v[12 + c] = t1 - t3;
    }
    // FWHT bits 2-7 (lane) via shfl_xor
#pragma unroll
    for (int m = 1; m <= 32; m <<= 1) {
#pragma unroll
        for (int r = 0; r < 16; ++r) {
            float p = __shfl_xor(v[r], m);
            v[r] = (lane & m) ? (p - v[r]) : (v[r] + p);
        }
    }
    // FWHT bits 8-9 (wave) via LDS
#pragma unroll
    for (int m = 64; m <= 128; m <<= 1) {
        __syncthreads();
#pragma unroll
        for (int r = 0; r < 16; ++r) s[r * 256 + tid] = v[r];
        __syncthreads();
#pragma unroll
        for (int r = 0; r < 16; ++r) {
            float p = s[r * 256 + (tid ^ m)];
            v[r] = (tid & m) ? (p - v[r]) : (v[r] + p);
        }
    }

    // absmax of fwht/64
    float mx = 0.f;
#pragma unroll
    for (int r = 0; r < 16; ++r) mx = fmaxf(mx, fabsf(v[r]));
#pragma unroll
    for (int o = 32; o > 0; o >>= 1) mx = fmaxf(mx, __shfl_xor(mx, o));
    __syncthreads();
    if (lane == 0) rb[tid >> 6] = mx;
    __syncthreads();
    float amraw = fmaxf(fmaxf(rb[0], rb[1]), fmaxf(rb[2], rb[3]));
    float amax = fmaxf(amraw * (1.0f / 64.0f), 1e-5f);
    float scale = 127.0f / amax;
    if (tid == 0) ainv[t] = amax * (1.0f / 127.0f);

    unsigned int* qr = (unsigned int*)(q + (size_t)t * PAD_F);
#pragma unroll
    for (int i = 0; i < 4; ++i) {
        unsigned int pk = 0;
#pragma unroll
        for (int c = 0; c < 4; ++c) {
            int qi = (int)rintf(v[4 * i + c] * (1.0f / 64.0f) * scale);
            qi = max(-128, min(127, qi));
            pk |= (unsigned)(qi & 255) << (8 * c);
        }
        qr[tid + i * 256] = pk;   // word index = slot/4 = tid + 256*i
    }
}

// ---------------- int8 MFMA GEMM, 256x256 tile, BK=64, paired-row LDS ----------------
// ROUND-6 VERBATIM (best verified: 141 us, MfmaUtil 42.6%, 0 bank conflicts).
// LDS row r (128B) holds matrix rows {2r, 2r+1}; chunk (par,h) stored at
// position (par*4+h) ^ (r&7); staging pre-swizzles the GLOBAL source (rule #21).
// 4-buffer ring, counted vmcnt(8), register-fragment double-buffer.
#define BK 64
#define NT (K_DIM / BK)   // 64

#define VMW(n) asm volatile("s_waitcnt vmcnt(" #n ")" ::: "memory")

__global__ __launch_bounds__(512, 2) void k_gemm(const signed char* __restrict__ Aq,
                                                 const signed char* __restrict__ Wq,
                                                 const float* __restrict__ ainv,
                                                 const float* __restrict__ wsp,
                                                 float* __restrict__ out) {
    __shared__ signed char sA[4][128 * 128];   // 4 x 16 KB (128 LDS-rows x 128B)
    __shared__ signed char sB[4][128 * 128];

    int tid = threadIdx.x;
    int lane = tid & 63, wid = tid >> 6;

    // XCD partition: XCD x owns bm in {4x..4x+3} (A L2-resident), sweeps bn.
    int bid = blockIdx.x;
    int xcd = bid & 7, li = bid >> 3;
    int bmb = xcd * 4 + (li & 3);
    int bnb = li >> 2;
    size_t bm0 = (size_t)bmb * 256, bn0 = (size_t)bnb * 256;

    int wm = wid >> 2, wn = wid & 3;          // 2M x 4N waves; wave tile 128x64

    // ---- staging decode: lane l writes LDS byte l*16 of a 1024B segment ----
    int rr = lane >> 3, pp = lane & 7;
    int Lg = pp ^ rr;
    int spar = Lg >> 2, sh = Lg & 3;
    const signed char* gA = Aq + (bm0 + (size_t)(wid * 32 + 2 * rr + spar)) * K_DIM + sh * 16;
    const signed char* gB = Wq + (bn0 + (size_t)(wid * 32 + 2 * rr + spar)) * K_DIM + sh * 16;

    // ---- fragment read constants (16x16x64: frag row fr, kseg hh) ----
    int fr = lane & 15, hh = lane >> 4;
    int pos = (((fr & 1) << 2) | hh) ^ (fr >> 1);
    int abase = (wm * 64 + (fr >> 1)) * 8 + pos;   // + mf*64
    int bbase = (wn * 32 + (fr >> 1)) * 8 + pos;   // + nf*64

    i32x4 acc[8][4];
#pragma unroll
    for (int m = 0; m < 8; ++m)
#pragma unroll
        for (int n = 0; n < 4; ++n) acc[m][n] = (i32x4){0, 0, 0, 0};

    i32x4 afA[8], bfA[4], afB[8], bfB[4];

    auto STAGE = [&](int b, int t) {
        size_t k0 = (size_t)t * BK;
        gload_lds16(gA + k0, &sA[b][(wid * 16) * 128]);
        gload_lds16(gA + k0 + (size_t)16 * K_DIM, &sA[b][(wid * 16 + 8) * 128]);
        gload_lds16(gB + k0, &sB[b][(wid * 16) * 128]);
        gload_lds16(gB + k0 + (size_t)16 * K_DIM, &sB[b][(wid * 16 + 8) * 128]);
    };

#define LOADF(B, AF, BF) do {                                           \
    const i32x4* va = (const i32x4*)&sA[B][0];                          \
    const i32x4* vb = (const i32x4*)&sB[B][0];                          \
    _Pragma("unroll")                                                   \
    for (int mf = 0; mf < 8; ++mf) AF[mf] = va[abase + mf * 64];        \
    _Pragma("unroll")                                                   \
    for (int nf = 0; nf < 4; ++nf) BF[nf] = vb[bbase + nf * 64];        \
} while (0)

#define COMPUTE(AF, BF) do {                                            \
    __builtin_amdgcn_s_setprio(1);                                      \
    _Pragma("unroll")                                                   \
    for (int mf = 0; mf < 8; ++mf)                                      \
        _Pragma("unroll")                                               \
        for (int nf = 0; nf < 4; ++nf)                                  \
            acc[mf][nf] = __builtin_amdgcn_mfma_i32_16x16x64_i8(        \
                AF[mf], BF[nf], acc[mf][nf], 0, 0, 0);                  \
    __builtin_amdgcn_s_setprio(0);                                      \
} while (0)

#define BODY(T, AFC, BFC, AFN, BFN) do {                                \
    STAGE((T + 3) & 3, T + 3);                                          \
    VMW(8);                                                             \
    __builtin_amdgcn_sched_barrier(0);                                  \
    __builtin_amdgcn_s_barrier();                                       \
    __builtin_amdgcn_sched_barrier(0);                                  \
    LOADF((T + 1) & 3, AFN, BFN);                                       \
    COMPUTE(AFC, BFC);                                                  \
    asm volatile("s_waitcnt lgkmcnt(0)" ::: "memory");                  \
    __builtin_amdgcn_sched_barrier(0);                                  \
} while (0)

    // prologue: 3 tiles in flight, tile 0 certified, frags(0) -> A set
    STAGE(0, 0);
    STAGE(1, 1);
    STAGE(2, 2);
    VMW(8);
    __builtin_amdgcn_sched_barrier(0);
    __builtin_amdgcn_s_barrier();
    __builtin_amdgcn_sched_barrier(0);
    LOADF(0, afA, bfA);
    asm volatile("s_waitcnt lgkmcnt(0)" ::: "memory");
    __builtin_amdgcn_sched_barrier(0);

#pragma unroll 1
    for (int t = 0; t < NT - 4; t += 2) {
        BODY(t, afA, bfA, afB, bfB);
        BODY(t + 1, afB, bfB, afA, bfA);
    }
    // t = 60: stages tile 63 (vmcnt(8) certifies 61), computes 60
    BODY(NT - 4, afA, bfA, afB, bfB);
    // t = 61: in-flight 62,63 -> vmcnt(4) certifies 62
    VMW(4);
    __builtin_amdgcn_sched_barrier(0);
    __builtin_amdgcn_s_barrier();
    __builtin_amdgcn_sched_barrier(0);
    LOADF(2, afA, bfA);
    COMPUTE(afB, bfB);
    asm volatile("s_waitcnt lgkmcnt(0)" ::: "memory");
    __builtin_amdgcn_sched_barrier(0);
    // t = 62: vmcnt(0) certifies 63
    VMW(0);
    __builtin_amdgcn_sched_barrier(0);
    __builtin_amdgcn_s_barrier();
    __builtin_amdgcn_sched_barrier(0);
    LOADF(3, afB, bfB);
    COMPUTE(afA, bfA);
    asm volatile("s_waitcnt lgkmcnt(0)" ::: "memory");
    __builtin_amdgcn_sched_barrier(0);
    // t = 63
    COMPUTE(afB, bfB);

    // epilogue: 16x16 C/D layout: col = lane&15, row = (lane>>4)*4 + reg
    float wsc = wsp[0];
#pragma unroll
    for (int mf = 0; mf < 8; ++mf) {
        size_t row0 = bm0 + wm * 128 + mf * 16 + hh * 4;
#pragma unroll
        for (int r = 0; r < 4; ++r) {
            size_t row = row0 + r;
            float sa = wsc * ainv[row];
#pragma unroll
            for (int nf = 0; nf < 4; ++nf) {
                size_t col = bn0 + wn * 64 + nf * 16 + fr;
                out[row * N_OUT + col] = (float)acc[mf][nf][r] * sa;
            }
        }
    }
#undef LOADF
#undef COMPUTE
#undef BODY
}

extern "C" void kernel_launch(void* const* d_in, const int* in_sizes, int n_in,
                              void* d_out, int out_size, void* d_ws, size_t ws_size,
                              hipStream_t stream) {
    const float* x     = (const float*)d_in[0];
    const float* gamma = (const float*)d_in[1];
    const float* beta  = (const float*)d_in[2];
    const float* w     = (const float*)d_in[3];
    float* out = (float*)d_out;
    char* ws = (char*)d_ws;

    signed char* q   = (signed char*)(ws + Q_OFF);
    signed char* wq  = (signed char*)(ws + WQ_OFF);
    float* ainv      = (float*)(ws + AINV_OFF);
    float* partial   = (float*)(ws + PART_OFF);
    float* wsp       = (float*)(ws + WSC_OFF);

    k_wabs<<<dim3(4096), dim3(256), 0, stream>>>(w, partial);
    k_wscale<<<dim3(1), dim3(256), 0, stream>>>(partial, wsp);
    k_wquant<<<dim3(16384), dim3(256), 0, stream>>>(w, wsp, (unsigned int*)wq);
    k_lnfwht<<<dim3(TOKENS), dim3(256), 0, stream>>>(x, gamma, beta, q, ainv);
    k_gemm<<<dim3(512), dim3(512), 0, stream>>>(q, wq, ainv, wsp, out);
}